// Round 6
// baseline (336.218 us; speedup 1.0000x reference)
//
#include <hip/hip_runtime.h>
#include <hip/hip_cooperative_groups.h>

namespace cg = cooperative_groups;

// B=32, T=2048, E=128, fp32. S (B,T,T) never materialized:
//   sx1[b]=sum_t x1[b,t,:], sx2[b]=sum_t x2[b,t,:]
//   w1[t]=x1[b,t].sx2[b]; c1=(1/T) sum_t w1[t]*x2[b,t,:]   (sym. for c2)
//   et1[t]=c1.U1[:,t] + x1[b,t].W1 + b1[t]; softmax; o1=sum_t at1[t]*x1[b,t,:]
// Primary: ONE cooperative kernel (512 blocks = 2/CU co-resident, ~60 VGPR),
// 4 phases split by grid.sync(). Fallback (checked return code): the proven
// round-5 4-kernel stream path.

#define B_ 32
#define T_ 2048
#define E_ 128
#define EV (E_/4)
#define INV_T (1.0f/2048.0f)

// ws float layout (every slot written before read -> no zeroing needed)
#define WS_PSX1 0                          // B*16*E  partial sx1
#define WS_PSX2 (B_*16*E_)                 // B*16*E  partial sx2
#define WS_PC1  (2*B_*16*E_)               // B*32*E  partial c1 (coop uses first 16/b)
#define WS_PC2  (2*B_*16*E_ + B_*32*E_)    // B*32*E  partial c2
#define WS_ET1  (2*B_*16*E_ + 2*B_*32*E_)  // B*T  (becomes probabilities)
#define WS_ET2  (WS_ET1 + B_*T_)           // B*T

__device__ __forceinline__ float dot4(float4 a, float4 b) {
    return a.x*b.x + a.y*b.y + a.z*b.z + a.w*b.w;
}
__device__ __forceinline__ void fma4(float4& a, float s, const float4 v) {
    a.x += s*v.x; a.y += s*v.y; a.z += s*v.z; a.w += s*v.w;
}
__device__ __forceinline__ void add4(float4& a, const float4 v) {
    a.x += v.x; a.y += v.y; a.z += v.z; a.w += v.w;
}
__device__ __forceinline__ float bfly32(float v) {
    #pragma unroll
    for (int m = 1; m <= 16; m <<= 1) v += __shfl_xor(v, m);
    return v;   // all 32 lanes hold the sum
}

// ==================== PRIMARY: single cooperative kernel ====================
__global__ __launch_bounds__(256, 2)
void fused(const float* __restrict__ x1, const float* __restrict__ x2,
           const float* __restrict__ W1, const float* __restrict__ b1,
           const float* __restrict__ U1, const float* __restrict__ W2,
           const float* __restrict__ b2, const float* __restrict__ U2,
           float* __restrict__ ws, float* __restrict__ out)
{
    __shared__ float4 s_r1[256], s_r2[256];          // 8 KB reduce scratch
    __shared__ float  s_a[E_], s_b[E_];              // sx / c staging
    __shared__ float  s_wa[E_], s_wb[E_];            // W1, W2
    __shared__ float  s_p1[128], s_p2[128];          // probabilities (P5)
    cg::grid_group grid = cg::this_grid();
    const int tid = threadIdx.x, bid = blockIdx.x;
    const int b = bid >> 4, g = bid & 15;            // batch, 128-row chunk
    const int rg = tid >> 5, q = tid & 31;

    if (tid < 128) s_wa[tid] = W1[tid];
    else           s_wb[tid - 128] = W2[tid - 128];
    __syncthreads();

    const float4* p1 = (const float4*)x1 + ((size_t)b*T_ + g*128)*EV;
    const float4* p2 = (const float4*)x2 + ((size_t)b*T_ + g*128)*EV;
    const float4* W1v = (const float4*)s_wa;
    const float4* W2v = (const float4*)s_wb;
    float* et1g = ws + WS_ET1 + (size_t)b*T_ + g*128;
    float* et2g = ws + WS_ET2 + (size_t)b*T_ + g*128;

    // ---- P1: partial column sums + et init (x.W + b), one pass over tile ----
    {
        float4 a1 = {0,0,0,0}, a2 = {0,0,0,0};
        #pragma unroll
        for (int i = 0; i < 16; ++i) {
            int r = i*8 + rg;
            float4 v1 = p1[r*EV + q];
            float4 v2 = p2[r*EV + q];
            add4(a1, v1); add4(a2, v2);
            float d1 = bfly32(dot4(v1, W1v[q]));
            float d2 = bfly32(dot4(v2, W2v[q]));
            if (q == 0) {
                int trow = g*128 + r;
                et1g[r] = d1 + b1[trow];
                et2g[r] = d2 + b2[trow];
            }
        }
        s_r1[tid] = a1; s_r2[tid] = a2;
        __syncthreads();
        for (int s = 128; s >= 32; s >>= 1) {
            if (tid < s) { add4(s_r1[tid], s_r1[tid+s]); add4(s_r2[tid], s_r2[tid+s]); }
            __syncthreads();
        }
        if (tid < 32) {
            ((float4*)(ws + WS_PSX1))[(b*16 + g)*EV + tid] = s_r1[tid];
            ((float4*)(ws + WS_PSX2))[(b*16 + g)*EV + tid] = s_r2[tid];
        }
        if (g == 0) out[b*2*E_ + tid] = 0.f;          // zero the output slice
    }
    grid.sync();

    // ---- P2: reduce psx -> sx; fused w + c accumulation (butterfly broadcast) ----
    {
        if (tid < 128) {
            float s = 0.f;
            #pragma unroll
            for (int gg = 0; gg < 16; ++gg) s += ws[WS_PSX1 + (b*16 + gg)*E_ + tid];
            s_a[tid] = s;                              // sx1
        } else {
            float s = 0.f;
            #pragma unroll
            for (int gg = 0; gg < 16; ++gg) s += ws[WS_PSX2 + (b*16 + gg)*E_ + (tid-128)];
            s_b[tid - 128] = s;                        // sx2
        }
        __syncthreads();
        const float4* sx1v = (const float4*)s_a;
        const float4* sx2v = (const float4*)s_b;
        float4 a1 = {0,0,0,0}, a2 = {0,0,0,0};
        #pragma unroll
        for (int i = 0; i < 16; ++i) {
            int r = i*8 + rg;
            float4 v1 = p1[r*EV + q];
            float4 v2 = p2[r*EV + q];
            float w1r = bfly32(dot4(v1, sx2v[q]));     // every lane gets w1[r]
            float w2r = bfly32(dot4(v2, sx1v[q]));
            fma4(a1, w1r, v2);                         // c1 partial
            fma4(a2, w2r, v1);                         // c2 partial
        }
        __syncthreads();                               // s_r reuse guard
        s_r1[tid] = a1; s_r2[tid] = a2;
        __syncthreads();
        for (int s = 128; s >= 32; s >>= 1) {
            if (tid < s) { add4(s_r1[tid], s_r1[tid+s]); add4(s_r2[tid], s_r2[tid+s]); }
            __syncthreads();
        }
        if (tid < 32) {
            float4 t1 = s_r1[tid], t2 = s_r2[tid];
            t1.x *= INV_T; t1.y *= INV_T; t1.z *= INV_T; t1.w *= INV_T;
            t2.x *= INV_T; t2.y *= INV_T; t2.z *= INV_T; t2.w *= INV_T;
            ((float4*)(ws + WS_PC1))[(b*16 + g)*EV + tid] = t1;
            ((float4*)(ws + WS_PC2))[(b*16 + g)*EV + tid] = t2;
        }
    }
    grid.sync();

    // ---- P3: c reduce, et += c.U, softmax -> probabilities (64 blocks) ----
    if (bid < 2*B_) {
        const int pb = bid >> 1, sel = bid & 1;
        const float* U  = sel ? U2 : U1;
        const float* pc = ws + (sel ? WS_PC2 : WS_PC1);
        float4* et4 = (float4*)(ws + (sel ? WS_ET2 : WS_ET1) + (size_t)pb*T_);
        if (tid < 128) {
            float s = 0.f;
            #pragma unroll
            for (int gg = 0; gg < 16; ++gg) s += pc[(pb*16 + gg)*E_ + tid];
            s_a[tid] = s;                              // c vector
        }
        __syncthreads();
        const float4* U4 = (const float4*)U;           // E x 512
        float4 acc0 = et4[tid];
        float4 acc1 = et4[tid + 256];
        #pragma unroll 4
        for (int e = 0; e < E_; ++e) {
            float ce = s_a[e];
            fma4(acc0, ce, U4[(size_t)e*(T_/4) + tid]);
            fma4(acc1, ce, U4[(size_t)e*(T_/4) + tid + 256]);
        }
        float* red = (float*)s_r1;
        float m = fmaxf(fmaxf(fmaxf(acc0.x, acc0.y), fmaxf(acc0.z, acc0.w)),
                        fmaxf(fmaxf(acc1.x, acc1.y), fmaxf(acc1.z, acc1.w)));
        red[tid] = m; __syncthreads();
        for (int s = 128; s > 0; s >>= 1) {
            if (tid < s) red[tid] = fmaxf(red[tid], red[tid+s]);
            __syncthreads();
        }
        m = red[0]; __syncthreads();
        float4 e0, e1;
        e0.x = __expf(acc0.x - m); e0.y = __expf(acc0.y - m);
        e0.z = __expf(acc0.z - m); e0.w = __expf(acc0.w - m);
        e1.x = __expf(acc1.x - m); e1.y = __expf(acc1.y - m);
        e1.z = __expf(acc1.z - m); e1.w = __expf(acc1.w - m);
        red[tid] = e0.x + e0.y + e0.z + e0.w + e1.x + e1.y + e1.z + e1.w;
        __syncthreads();
        for (int s = 128; s > 0; s >>= 1) {
            if (tid < s) red[tid] += red[tid+s];
            __syncthreads();
        }
        float il = 1.f / red[0];
        e0.x *= il; e0.y *= il; e0.z *= il; e0.w *= il;
        e1.x *= il; e1.y *= il; e1.z *= il; e1.w *= il;
        et4[tid]       = e0;
        et4[tid + 256] = e1;
    }
    grid.sync();

    // ---- P5: o = sum_t at[t]*x[t,:] ----
    {
        if (tid < 128) s_p1[tid] = et1g[tid];
        else           s_p2[tid - 128] = et2g[tid - 128];
        __syncthreads();
        float4 a1 = {0,0,0,0}, a2 = {0,0,0,0};
        #pragma unroll
        for (int i = 0; i < 16; ++i) {
            int r = i*8 + rg;
            fma4(a1, s_p1[r], p1[r*EV + q]);
            fma4(a2, s_p2[r], p2[r*EV + q]);
        }
        s_r1[tid] = a1; s_r2[tid] = a2;
        __syncthreads();
        for (int s = 128; s >= 32; s >>= 1) {
            if (tid < s) { add4(s_r1[tid], s_r1[tid+s]); add4(s_r2[tid], s_r2[tid+s]); }
            __syncthreads();
        }
        if (tid < 32) {
            float4 t1 = s_r1[tid], t2 = s_r2[tid];
            atomicAdd(&out[b*2*E_ + tid*4+0], t1.x);
            atomicAdd(&out[b*2*E_ + tid*4+1], t1.y);
            atomicAdd(&out[b*2*E_ + tid*4+2], t1.z);
            atomicAdd(&out[b*2*E_ + tid*4+3], t1.w);
            atomicAdd(&out[b*2*E_ + E_ + tid*4+0], t2.x);
            atomicAdd(&out[b*2*E_ + E_ + tid*4+1], t2.y);
            atomicAdd(&out[b*2*E_ + E_ + tid*4+2], t2.z);
            atomicAdd(&out[b*2*E_ + E_ + tid*4+3], t2.w);
        }
    }
}

// ==================== FALLBACK: proven round-5 4-kernel path ====================
__global__ __launch_bounds__(256)
void k1_psx(const float* __restrict__ x1, const float* __restrict__ x2,
            float* __restrict__ ws) {
    __shared__ float4 s_r1[256], s_r2[256];
    const int b = blockIdx.x, g = blockIdx.y, tid = threadIdx.x;
    const float4* p1 = (const float4*)x1 + ((size_t)b*T_ + g*128)*EV;
    const float4* p2 = (const float4*)x2 + ((size_t)b*T_ + g*128)*EV;
    const int rg = tid >> 5, q = tid & 31;
    float4 a1 = {0,0,0,0}, a2 = {0,0,0,0};
    #pragma unroll
    for (int i = 0; i < 16; ++i) {
        int r = i*8 + rg;
        add4(a1, p1[r*EV + q]);
        add4(a2, p2[r*EV + q]);
    }
    s_r1[tid] = a1; s_r2[tid] = a2;
    __syncthreads();
    for (int s = 128; s >= 32; s >>= 1) {
        if (tid < s) { add4(s_r1[tid], s_r1[tid+s]); add4(s_r2[tid], s_r2[tid+s]); }
        __syncthreads();
    }
    if (tid < 32) {
        ((float4*)(ws + WS_PSX1))[(b*16 + g)*EV + tid] = s_r1[tid];
        ((float4*)(ws + WS_PSX2))[(b*16 + g)*EV + tid] = s_r2[tid];
    }
}

__global__ __launch_bounds__(256)
void k2_wc(const float* __restrict__ x1, const float* __restrict__ x2,
           const float* __restrict__ W1, const float* __restrict__ b1,
           const float* __restrict__ W2, const float* __restrict__ b2,
           float* __restrict__ ws) {
    __shared__ float4 s_r1[256], s_r2[256];
    __shared__ float  s_a[E_], s_b[E_], s_wa[E_], s_wb[E_];
    const int b = blockIdx.x, ch = blockIdx.y, tid = threadIdx.x;
    if (tid < E_) {
        float sa = 0.f, sb = 0.f;
        #pragma unroll
        for (int g = 0; g < 16; ++g) {
            sa += ws[WS_PSX1 + (b*16 + g)*E_ + tid];
            sb += ws[WS_PSX2 + (b*16 + g)*E_ + tid];
        }
        s_a[tid] = sa; s_b[tid] = sb;
        s_wa[tid] = W1[tid]; s_wb[tid] = W2[tid];
    }
    __syncthreads();
    const float4* p1 = (const float4*)x1 + ((size_t)b*T_ + ch*64)*EV;
    const float4* p2 = (const float4*)x2 + ((size_t)b*T_ + ch*64)*EV;
    const float4* sx1v = (const float4*)s_a;
    const float4* sx2v = (const float4*)s_b;
    const float4* W1v  = (const float4*)s_wa;
    const float4* W2v  = (const float4*)s_wb;
    const int rowoff = tid >> 5, q = tid & 31;
    float* et1 = ws + WS_ET1 + (size_t)b*T_ + ch*64;
    float* et2 = ws + WS_ET2 + (size_t)b*T_ + ch*64;
    float4 a1 = {0,0,0,0}, a2 = {0,0,0,0};
    #pragma unroll
    for (int i = 0; i < 8; ++i) {
        int r = i*8 + rowoff;
        float4 v1 = p1[r*EV + q];
        float4 v2 = p2[r*EV + q];
        float pw1 = bfly32(dot4(v1, sx2v[q]));
        float px1 = bfly32(dot4(v1, W1v[q]));
        float pw2 = bfly32(dot4(v2, sx1v[q]));
        float px2 = bfly32(dot4(v2, W2v[q]));
        if (q == 0) {
            int trow = ch*64 + r;
            et1[r] = px1 + b1[trow];
            et2[r] = px2 + b2[trow];
        }
        fma4(a1, pw1, v2);
        fma4(a2, pw2, v1);
    }
    s_r1[tid] = a1; s_r2[tid] = a2;
    __syncthreads();
    for (int s = 128; s >= 32; s >>= 1) {
        if (tid < s) { add4(s_r1[tid], s_r1[tid+s]); add4(s_r2[tid], s_r2[tid+s]); }
        __syncthreads();
    }
    if (tid < 32) {
        float4 t1 = s_r1[tid], t2 = s_r2[tid];
        t1.x *= INV_T; t1.y *= INV_T; t1.z *= INV_T; t1.w *= INV_T;
        t2.x *= INV_T; t2.y *= INV_T; t2.z *= INV_T; t2.w *= INV_T;
        ((float4*)(ws + WS_PC1))[(b*32 + ch)*EV + tid] = t1;
        ((float4*)(ws + WS_PC2))[(b*32 + ch)*EV + tid] = t2;
    }
}

__global__ __launch_bounds__(512)
void k3_et_softmax(const float* __restrict__ U1, const float* __restrict__ U2,
                   float* __restrict__ ws, float* __restrict__ out) {
    __shared__ float s_c[E_];
    __shared__ float red[512];
    const int b = blockIdx.x, sel = blockIdx.y, tid = threadIdx.x;
    const float* U = sel ? U2 : U1;
    const float* pc = ws + (sel ? WS_PC2 : WS_PC1);
    float4* et4 = (float4*)(ws + (sel ? WS_ET2 : WS_ET1) + (size_t)b*T_);
    if (tid < E_) {
        float s = 0.f;
        #pragma unroll
        for (int ch = 0; ch < 32; ++ch) s += pc[(b*32 + ch)*E_ + tid];
        s_c[tid] = s;
    } else if (tid >= 256 && tid < 256 + E_) {
        out[b*2*E_ + sel*E_ + (tid - 256)] = 0.f;
    }
    __syncthreads();
    const float4* U4 = (const float4*)U;
    float4 acc = et4[tid];
    #pragma unroll 4
    for (int e = 0; e < E_; ++e) fma4(acc, s_c[e], U4[(size_t)e*(T_/4) + tid]);
    float m = fmaxf(fmaxf(acc.x, acc.y), fmaxf(acc.z, acc.w));
    red[tid] = m; __syncthreads();
    for (int s = 256; s > 0; s >>= 1) {
        if (tid < s) red[tid] = fmaxf(red[tid], red[tid+s]);
        __syncthreads();
    }
    m = red[0]; __syncthreads();
    float4 e4;
    e4.x = __expf(acc.x - m); e4.y = __expf(acc.y - m);
    e4.z = __expf(acc.z - m); e4.w = __expf(acc.w - m);
    red[tid] = e4.x + e4.y + e4.z + e4.w;
    __syncthreads();
    for (int s = 256; s > 0; s >>= 1) {
        if (tid < s) red[tid] += red[tid+s];
        __syncthreads();
    }
    float il = 1.f / red[0];
    e4.x *= il; e4.y *= il; e4.z *= il; e4.w *= il;
    et4[tid] = e4;
}

__global__ __launch_bounds__(256)
void k5_out(const float* __restrict__ x1, const float* __restrict__ x2,
            const float* __restrict__ ws, float* __restrict__ out) {
    __shared__ float4 s_r1[256], s_r2[256];
    __shared__ float s_p1[128], s_p2[128];
    const int b = blockIdx.x, g = blockIdx.y, tid = threadIdx.x;
    const float* pr1 = ws + WS_ET1 + (size_t)b*T_ + g*128;
    const float* pr2 = ws + WS_ET2 + (size_t)b*T_ + g*128;
    if (tid < 128) s_p1[tid] = pr1[tid];
    else           s_p2[tid - 128] = pr2[tid - 128];
    __syncthreads();
    const float4* p1 = (const float4*)x1 + ((size_t)b*T_ + g*128)*EV;
    const float4* p2 = (const float4*)x2 + ((size_t)b*T_ + g*128)*EV;
    const int rg = tid >> 5, q = tid & 31;
    float4 a1 = {0,0,0,0}, a2 = {0,0,0,0};
    #pragma unroll
    for (int i = 0; i < 16; ++i) {
        int r = i*8 + rg;
        fma4(a1, s_p1[r], p1[r*EV + q]);
        fma4(a2, s_p2[r], p2[r*EV + q]);
    }
    s_r1[tid] = a1; s_r2[tid] = a2;
    __syncthreads();
    for (int s = 128; s >= 32; s >>= 1) {
        if (tid < s) { add4(s_r1[tid], s_r1[tid+s]); add4(s_r2[tid], s_r2[tid+s]); }
        __syncthreads();
    }
    if (tid < 32) {
        float4 t1 = s_r1[tid], t2 = s_r2[tid];
        atomicAdd(&out[b*2*E_ + tid*4+0], t1.x);
        atomicAdd(&out[b*2*E_ + tid*4+1], t1.y);
        atomicAdd(&out[b*2*E_ + tid*4+2], t1.z);
        atomicAdd(&out[b*2*E_ + tid*4+3], t1.w);
        atomicAdd(&out[b*2*E_ + E_ + tid*4+0], t2.x);
        atomicAdd(&out[b*2*E_ + E_ + tid*4+1], t2.y);
        atomicAdd(&out[b*2*E_ + E_ + tid*4+2], t2.z);
        atomicAdd(&out[b*2*E_ + E_ + tid*4+3], t2.w);
    }
}

extern "C" void kernel_launch(void* const* d_in, const int* in_sizes, int n_in,
                              void* d_out, int out_size, void* d_ws, size_t ws_size,
                              hipStream_t stream) {
    const float* x1 = (const float*)d_in[0];
    const float* x2 = (const float*)d_in[1];
    const float* W1 = (const float*)d_in[2];
    const float* b1 = (const float*)d_in[3];
    const float* U1 = (const float*)d_in[4];
    const float* W2 = (const float*)d_in[5];
    const float* b2 = (const float*)d_in[6];
    const float* U2 = (const float*)d_in[7];
    float* ws  = (float*)d_ws;
    float* out = (float*)d_out;

    void* args[] = { (void*)&x1, (void*)&x2, (void*)&W1, (void*)&b1, (void*)&U1,
                     (void*)&W2, (void*)&b2, (void*)&U2, (void*)&ws, (void*)&out };
    hipError_t err = hipLaunchCooperativeKernel((void*)fused, dim3(512), dim3(256),
                                                args, 0, stream);
    if (err != hipSuccess) {
        (void)hipGetLastError();   // clear sticky error, take the proven 4-kernel path
        k1_psx<<<dim3(B_, 16), 256, 0, stream>>>(x1, x2, ws);
        k2_wc<<<dim3(B_, 32), 256, 0, stream>>>(x1, x2, W1, b1, W2, b2, ws);
        k3_et_softmax<<<dim3(B_, 2), 512, 0, stream>>>(U1, U2, ws, out);
        k5_out<<<dim3(B_, 16), 256, 0, stream>>>(x1, x2, ws, out);
    }
}

// Round 7
// 158.898 us; speedup vs baseline: 2.1159x; 2.1159x over previous
//
#include <hip/hip_runtime.h>

// B=32, T=2048, E=128, fp32. S (B,T,T) never materialized:
//   sx1[b]=sum_t x1[b,t,:], sx2[b]=sum_t x2[b,t,:]
//   w1[t]=x1[b,t].sx2[b]; c1=(1/T) sum_t w1[t]*x2[b,t,:]   (sym. for c2)
//   et1[t]=c1.U1[:,t] + x1[b,t].W1 + b1[t]; softmax; o1=sum_t at1[t]*x1[b,t,:]
// 4 plain launches. Cooperative grid.sync measured at ~70us/sync on gfx950
// (R6: 240us kernel, 35us work) -> kernel boundaries (~4.5us) are cheaper.

#define B_ 32
#define T_ 2048
#define E_ 128
#define EV (E_/4)
#define INV_T (1.0f/2048.0f)

// ws float layout (every slot written before read -> no zeroing needed)
#define WS_PSX1 0                          // B*16*E  partial sx1
#define WS_PSX2 (B_*16*E_)                 // B*16*E  partial sx2
#define WS_PC1  (2*B_*16*E_)               // B*16*E  partial c1
#define WS_PC2  (3*B_*16*E_)               // B*16*E  partial c2
#define WS_ET1  (4*B_*16*E_)               // B*T  (becomes probabilities)
#define WS_ET2  (WS_ET1 + B_*T_)           // B*T

__device__ __forceinline__ float dot4(float4 a, float4 b) {
    return a.x*b.x + a.y*b.y + a.z*b.z + a.w*b.w;
}
__device__ __forceinline__ void fma4(float4& a, float s, const float4 v) {
    a.x += s*v.x; a.y += s*v.y; a.z += s*v.z; a.w += s*v.w;
}
__device__ __forceinline__ void add4(float4& a, const float4 v) {
    a.x += v.x; a.y += v.y; a.z += v.z; a.w += v.w;
}
__device__ __forceinline__ float bfly32(float v) {
    #pragma unroll
    for (int m = 1; m <= 16; m <<= 1) v += __shfl_xor(v, m);
    return v;   // all 32 lanes hold the sum
}

// ---- K1: partial column sums + et init (x.W + b), one x pass (proven: R6 P1) ----
__global__ __launch_bounds__(256)
void k1_psx_et(const float* __restrict__ x1, const float* __restrict__ x2,
               const float* __restrict__ W1, const float* __restrict__ b1,
               const float* __restrict__ W2, const float* __restrict__ b2,
               float* __restrict__ ws) {
    __shared__ float4 s_r1[256], s_r2[256];
    __shared__ float  s_wa[E_], s_wb[E_];
    const int b = blockIdx.x, g = blockIdx.y, tid = threadIdx.x;
    if (tid < 128) s_wa[tid] = W1[tid];
    else           s_wb[tid - 128] = W2[tid - 128];
    __syncthreads();
    const float4* p1 = (const float4*)x1 + ((size_t)b*T_ + g*128)*EV;
    const float4* p2 = (const float4*)x2 + ((size_t)b*T_ + g*128)*EV;
    const float4* W1v = (const float4*)s_wa;
    const float4* W2v = (const float4*)s_wb;
    float* et1g = ws + WS_ET1 + (size_t)b*T_ + g*128;
    float* et2g = ws + WS_ET2 + (size_t)b*T_ + g*128;
    const int rg = tid >> 5, q = tid & 31;
    float4 a1 = {0,0,0,0}, a2 = {0,0,0,0};
    #pragma unroll
    for (int i = 0; i < 16; ++i) {
        int r = i*8 + rg;
        float4 v1 = p1[r*EV + q];
        float4 v2 = p2[r*EV + q];
        add4(a1, v1); add4(a2, v2);
        float d1 = bfly32(dot4(v1, W1v[q]));
        float d2 = bfly32(dot4(v2, W2v[q]));
        if (q == 0) {
            int trow = g*128 + r;
            et1g[r] = d1 + b1[trow];
            et2g[r] = d2 + b2[trow];
        }
    }
    s_r1[tid] = a1; s_r2[tid] = a2;
    __syncthreads();
    for (int s = 128; s >= 32; s >>= 1) {
        if (tid < s) { add4(s_r1[tid], s_r1[tid+s]); add4(s_r2[tid], s_r2[tid+s]); }
        __syncthreads();
    }
    if (tid < 32) {
        ((float4*)(ws + WS_PSX1))[(b*16 + g)*EV + tid] = s_r1[tid];
        ((float4*)(ws + WS_PSX2))[(b*16 + g)*EV + tid] = s_r2[tid];
    }
}

// ---- K2: reduce psx -> sx; fused w + c accumulation (proven: R6 P2) ----
__global__ __launch_bounds__(256)
void k2_wc(const float* __restrict__ x1, const float* __restrict__ x2,
           float* __restrict__ ws) {
    __shared__ float4 s_r1[256], s_r2[256];
    __shared__ float  s_a[E_], s_b[E_];
    const int b = blockIdx.x, g = blockIdx.y, tid = threadIdx.x;
    if (tid < 128) {
        float s = 0.f;
        #pragma unroll
        for (int gg = 0; gg < 16; ++gg) s += ws[WS_PSX1 + (b*16 + gg)*E_ + tid];
        s_a[tid] = s;                              // sx1
    } else {
        float s = 0.f;
        #pragma unroll
        for (int gg = 0; gg < 16; ++gg) s += ws[WS_PSX2 + (b*16 + gg)*E_ + (tid-128)];
        s_b[tid - 128] = s;                        // sx2
    }
    __syncthreads();
    const float4* p1 = (const float4*)x1 + ((size_t)b*T_ + g*128)*EV;
    const float4* p2 = (const float4*)x2 + ((size_t)b*T_ + g*128)*EV;
    const float4* sx1v = (const float4*)s_a;
    const float4* sx2v = (const float4*)s_b;
    const int rg = tid >> 5, q = tid & 31;
    float4 a1 = {0,0,0,0}, a2 = {0,0,0,0};
    #pragma unroll
    for (int i = 0; i < 16; ++i) {
        int r = i*8 + rg;
        float4 v1 = p1[r*EV + q];
        float4 v2 = p2[r*EV + q];
        float w1r = bfly32(dot4(v1, sx2v[q]));     // every lane gets w1[r]
        float w2r = bfly32(dot4(v2, sx1v[q]));
        fma4(a1, w1r, v2);                         // c1 partial
        fma4(a2, w2r, v1);                         // c2 partial
    }
    s_r1[tid] = a1; s_r2[tid] = a2;
    __syncthreads();
    for (int s = 128; s >= 32; s >>= 1) {
        if (tid < s) { add4(s_r1[tid], s_r1[tid+s]); add4(s_r2[tid], s_r2[tid+s]); }
        __syncthreads();
    }
    if (tid < 32) {
        float4 t1 = s_r1[tid], t2 = s_r2[tid];
        t1.x *= INV_T; t1.y *= INV_T; t1.z *= INV_T; t1.w *= INV_T;
        t2.x *= INV_T; t2.y *= INV_T; t2.z *= INV_T; t2.w *= INV_T;
        ((float4*)(ws + WS_PC1))[(b*16 + g)*EV + tid] = t1;
        ((float4*)(ws + WS_PC2))[(b*16 + g)*EV + tid] = t2;
    }
}

// ---- K3: reduce c, et += c.U (4-way acc split), softmax -> probs; zero out ----
__global__ __launch_bounds__(512)
void k3_et_softmax(const float* __restrict__ U1, const float* __restrict__ U2,
                   float* __restrict__ ws, float* __restrict__ out) {
    __shared__ float s_c[E_];
    __shared__ float red[512];
    const int b = blockIdx.x, sel = blockIdx.y, tid = threadIdx.x;
    const float* U = sel ? U2 : U1;
    const float* pc = ws + (sel ? WS_PC2 : WS_PC1);
    float4* et4 = (float4*)(ws + (sel ? WS_ET2 : WS_ET1) + (size_t)b*T_);
    if (tid < E_) {
        float s = 0.f;
        #pragma unroll
        for (int gg = 0; gg < 16; ++gg) s += pc[(b*16 + gg)*E_ + tid];
        s_c[tid] = s;
    } else if (tid >= 256 && tid < 256 + E_) {
        out[b*2*E_ + sel*E_ + (tid - 256)] = 0.f;
    }
    __syncthreads();
    const float4* U4 = (const float4*)U;           // E x 512
    float4 accA = et4[tid];                        // et init (x.W + b)
    float4 accB = {0,0,0,0}, accC = {0,0,0,0}, accD = {0,0,0,0};
    #pragma unroll 2
    for (int e = 0; e < E_; e += 4) {              // 4 independent chains
        fma4(accA, s_c[e+0], U4[(size_t)(e+0)*(T_/4) + tid]);
        fma4(accB, s_c[e+1], U4[(size_t)(e+1)*(T_/4) + tid]);
        fma4(accC, s_c[e+2], U4[(size_t)(e+2)*(T_/4) + tid]);
        fma4(accD, s_c[e+3], U4[(size_t)(e+3)*(T_/4) + tid]);
    }
    add4(accA, accB); add4(accC, accD); add4(accA, accC);
    float m = fmaxf(fmaxf(accA.x, accA.y), fmaxf(accA.z, accA.w));
    red[tid] = m; __syncthreads();
    for (int s = 256; s > 0; s >>= 1) {
        if (tid < s) red[tid] = fmaxf(red[tid], red[tid+s]);
        __syncthreads();
    }
    m = red[0]; __syncthreads();
    float4 e4;
    e4.x = __expf(accA.x - m); e4.y = __expf(accA.y - m);
    e4.z = __expf(accA.z - m); e4.w = __expf(accA.w - m);
    red[tid] = e4.x + e4.y + e4.z + e4.w;
    __syncthreads();
    for (int s = 256; s > 0; s >>= 1) {
        if (tid < s) red[tid] += red[tid+s];
        __syncthreads();
    }
    float il = 1.f / red[0];
    e4.x *= il; e4.y *= il; e4.z *= il; e4.w *= il;
    et4[tid] = e4;                                 // et now holds at[t]
}

// ---- K5: o = sum_t at[t]*x[t,:] (proven: R5) ----
__global__ __launch_bounds__(256)
void k5_out(const float* __restrict__ x1, const float* __restrict__ x2,
            const float* __restrict__ ws, float* __restrict__ out) {
    __shared__ float4 s_r1[256], s_r2[256];
    __shared__ float s_p1[128], s_p2[128];
    const int b = blockIdx.x, g = blockIdx.y, tid = threadIdx.x;
    const float* pr1 = ws + WS_ET1 + (size_t)b*T_ + g*128;
    const float* pr2 = ws + WS_ET2 + (size_t)b*T_ + g*128;
    if (tid < 128) s_p1[tid] = pr1[tid];
    else           s_p2[tid - 128] = pr2[tid - 128];
    __syncthreads();
    const float4* p1 = (const float4*)x1 + ((size_t)b*T_ + g*128)*EV;
    const float4* p2 = (const float4*)x2 + ((size_t)b*T_ + g*128)*EV;
    const int rg = tid >> 5, q = tid & 31;
    float4 a1 = {0,0,0,0}, a2 = {0,0,0,0};
    #pragma unroll
    for (int i = 0; i < 16; ++i) {
        int r = i*8 + rg;
        fma4(a1, s_p1[r], p1[r*EV + q]);
        fma4(a2, s_p2[r], p2[r*EV + q]);
    }
    s_r1[tid] = a1; s_r2[tid] = a2;
    __syncthreads();
    for (int s = 128; s >= 32; s >>= 1) {
        if (tid < s) { add4(s_r1[tid], s_r1[tid+s]); add4(s_r2[tid], s_r2[tid+s]); }
        __syncthreads();
    }
    if (tid < 32) {
        float4 t1 = s_r1[tid], t2 = s_r2[tid];
        atomicAdd(&out[b*2*E_ + tid*4+0], t1.x);
        atomicAdd(&out[b*2*E_ + tid*4+1], t1.y);
        atomicAdd(&out[b*2*E_ + tid*4+2], t1.z);
        atomicAdd(&out[b*2*E_ + tid*4+3], t1.w);
        atomicAdd(&out[b*2*E_ + E_ + tid*4+0], t2.x);
        atomicAdd(&out[b*2*E_ + E_ + tid*4+1], t2.y);
        atomicAdd(&out[b*2*E_ + E_ + tid*4+2], t2.z);
        atomicAdd(&out[b*2*E_ + E_ + tid*4+3], t2.w);
    }
}

extern "C" void kernel_launch(void* const* d_in, const int* in_sizes, int n_in,
                              void* d_out, int out_size, void* d_ws, size_t ws_size,
                              hipStream_t stream) {
    const float* x1 = (const float*)d_in[0];
    const float* x2 = (const float*)d_in[1];
    const float* W1 = (const float*)d_in[2];
    const float* b1 = (const float*)d_in[3];
    const float* U1 = (const float*)d_in[4];
    const float* W2 = (const float*)d_in[5];
    const float* b2 = (const float*)d_in[6];
    const float* U2 = (const float*)d_in[7];
    float* ws  = (float*)d_ws;
    float* out = (float*)d_out;

    k1_psx_et<<<dim3(B_, 16), 256, 0, stream>>>(x1, x2, W1, b1, W2, b2, ws);
    k2_wc<<<dim3(B_, 16), 256, 0, stream>>>(x1, x2, ws);
    k3_et_softmax<<<dim3(B_, 2), 512, 0, stream>>>(U1, U2, ws, out);
    k5_out<<<dim3(B_, 16), 256, 0, stream>>>(x1, x2, ws, out);
}